// Round 12
// baseline (2373.661 us; speedup 1.0000x reference)
//
#include <hip/hip_runtime.h>

#define N_NODES 50000
#define N_EDGES 800000

#define HIST_BLOCKS 3125   // ceil(800000/256)
#define CONV_BLOCKS 1563   // ceil(50000*8/256)
#define PREP_BLOCKS 160    // ceil(2*20480/256)

typedef unsigned int uint;
typedef unsigned short ushort;

typedef __attribute__((ext_vector_type(8))) short short8;
typedef __attribute__((ext_vector_type(4))) float floatx4;
typedef __attribute__((ext_vector_type(4))) uint uintx4;

__device__ __forceinline__ ushort f2bf(float f) {
    uint u = __builtin_bit_cast(uint, f);
    u += 0x7fffu + ((u >> 16) & 1u);      // round-to-nearest-even
    return (ushort)(u >> 16);
}
__device__ __forceinline__ float bf2f(ushort h) {
    uint u = ((uint)h) << 16;
    return __builtin_bit_cast(float, u);
}
__device__ __forceinline__ float bflo(uint w) { return __builtin_bit_cast(float, w << 16); }
__device__ __forceinline__ float bfhi(uint w) { return __builtin_bit_cast(float, w & 0xffff0000u); }
__device__ __forceinline__ uint pack2(float a, float b) {
    return (uint)f2bf(a) | ((uint)f2bf(b) << 16);
}

// ---------------- fused setup: hist + x->bf16 conv + weight swizzle ----------------

__global__ __launch_bounds__(256) void setup_k(const int* __restrict__ ei,
                                               int* __restrict__ counts,
                                               const float* __restrict__ x,
                                               ushort* __restrict__ hb,
                                               const float* __restrict__ basis,
                                               const float* __restrict__ root,
                                               ushort* __restrict__ Bsw) {
    int b = blockIdx.x;
    int tid = threadIdx.x;
    if (b < HIST_BLOCKS) {
        int e = b * 256 + tid;
        if (e < N_EDGES) atomicAdd(&counts[ei[N_EDGES + e]], 1);
    } else if (b < HIST_BLOCKS + CONV_BLOCKS) {
        int i = (b - HIST_BLOCKS) * 256 + tid;
        if (i < N_NODES * 8) {
            const float4* p = (const float4*)(x + (size_t)i * 8);
            float4 a = p[0], bb = p[1];
            uint4 o;
            o.x = pack2(a.x, a.y); o.y = pack2(a.z, a.w);
            o.z = pack2(bb.x, bb.y); o.w = pack2(bb.z, bb.w);
            *(uint4*)(hb + (size_t)i * 8) = o;
        }
    } else {
        int idx = (b - HIST_BLOCKS - CONV_BLOCKS) * 256 + tid;
        if (idx < 2 * 20480) {
            int l = idx / 20480;
            int r = idx % 20480;
            int kb = r >> 11, ct = (r >> 9) & 3, q = (r >> 7) & 3, n = (r >> 3) & 15, j = r & 7;
            int k = kb * 32 + q * 8 + j;
            int c = ct * 16 + n;
            float v = (k < 256) ? basis[(size_t)l * 16384 + k * 64 + c]
                                : root[(size_t)l * 4096 + (k - 256) * 64 + c];
            Bsw[idx] = f2bf(v);
        }
    }
}

// ---------------- scan ----------------

__global__ __launch_bounds__(1024) void scan1_k(const int* __restrict__ counts,
                                                int* __restrict__ start,
                                                int* __restrict__ bsums) {
    __shared__ int s[1024];
    int i = blockIdx.x * 1024 + threadIdx.x;
    int x = (i < N_NODES) ? counts[i] : 0;
    s[threadIdx.x] = x;
    __syncthreads();
    for (int off = 1; off < 1024; off <<= 1) {
        int v = (threadIdx.x >= off) ? s[threadIdx.x - off] : 0;
        __syncthreads();
        s[threadIdx.x] += v;
        __syncthreads();
    }
    if (i < N_NODES) start[i] = s[threadIdx.x] - x;
    if (threadIdx.x == 1023) bsums[blockIdx.x] = s[1023];
}

// wave-parallel exclusive scan over <=64 block sums (was a 49-iter serial chain)
__global__ __launch_bounds__(64) void scan2_k(int* __restrict__ bsums, int n) {
    int lane = threadIdx.x;
    int own = (lane < n) ? bsums[lane] : 0;
    int v = own;
    #pragma unroll
    for (int off = 1; off < 64; off <<= 1) {
        int u = __shfl_up(v, off);
        if (lane >= off) v += u;
    }
    if (lane < n) bsums[lane] = v - own;
}

__global__ __launch_bounds__(256) void scan3_k(int* __restrict__ start,
                                               int* __restrict__ cursor,
                                               const int* __restrict__ bsums) {
    int i = blockIdx.x * 256 + threadIdx.x;
    if (i < N_NODES) {
        int v = start[i] + bsums[i >> 10];
        start[i] = v;
        cursor[i] = v;
    }
}

// fused: per edge compute both layers' c = ea @ att, scatter ONE 64B-line record pair.
// pad word now carries dst so the agg kernel can demux block-shared edge ranges.
__global__ __launch_bounds__(256) void scatter_k(const int* __restrict__ ei,
                                                 const float* __restrict__ ea,
                                                 const float* __restrict__ att,   // [2,8,4]
                                                 int* __restrict__ cursor,
                                                 uintx4* __restrict__ rec) {
    int e = blockIdx.x * 256 + threadIdx.x;
    if (e >= N_EDGES) return;
    int src = ei[e];
    int dst = ei[N_EDGES + e];

    const float4* eav = (const float4*)(ea + (size_t)e * 8);
    float4 a0 = eav[0], a1 = eav[1];
    float ev[8] = {a0.x, a0.y, a0.z, a0.w, a1.x, a1.y, a1.z, a1.w};

    float4 c0 = make_float4(0.f, 0.f, 0.f, 0.f);
    float4 c1 = make_float4(0.f, 0.f, 0.f, 0.f);
    const float4* att0 = (const float4*)att;
    const float4* att1 = (const float4*)(att + 32);
    #pragma unroll
    for (int r = 0; r < 8; ++r) {
        float4 w0 = att0[r];
        float4 w1 = att1[r];
        c0.x = fmaf(ev[r], w0.x, c0.x); c0.y = fmaf(ev[r], w0.y, c0.y);
        c0.z = fmaf(ev[r], w0.z, c0.z); c0.w = fmaf(ev[r], w0.w, c0.w);
        c1.x = fmaf(ev[r], w1.x, c1.x); c1.y = fmaf(ev[r], w1.y, c1.y);
        c1.z = fmaf(ev[r], w1.z, c1.z); c1.w = fmaf(ev[r], w1.w, c1.w);
    }
    int pos = atomicAdd(&cursor[dst], 1);
    uintx4 r0 = {(uint)src, pack2(c0.x, c0.y), pack2(c0.z, c0.w), (uint)dst};
    uintx4 r1 = {(uint)src, pack2(c1.x, c1.y), pack2(c1.z, c1.w), (uint)dst};
    rec[2 * (size_t)pos]     = r0;
    rec[2 * (size_t)pos + 1] = r1;
}

// ---------------- fused per-layer kernel: aggregate + MFMA GEMM ----------------
// Block = 16 nodes = contiguous CSR range. 16 waves share the block's whole edge list
// (balanced chunks, no per-node degree tail), accumulating into fp32 LDS via ds_add_f32;
// row = rec.pad & 15. Then waves 0..3 run the 16x64 MFMA tile (K=320).
__global__ __launch_bounds__(1024) void aggmm_k(const int* __restrict__ start,
                                                const uintx4* __restrict__ recs,   // rec (+1 for layer 1)
                                                const ushort* __restrict__ hb,     // [N][64] bf16
                                                const ushort* __restrict__ Bsw,    // [2560][8] bf16 frag order
                                                const float* __restrict__ bias,    // [64]
                                                float* __restrict__ outf,          // fp32 out or null
                                                ushort* __restrict__ outh,         // next hb or null
                                                int relu) {
    __shared__ float ysf[16][260];   // fp32 accumulators, +4 pad

    const int tid = threadIdx.x;
    const int lane = tid & 63;
    const int wid = tid >> 6;        // 0..15
    const int m0 = blockIdx.x * 16;

    // zero accumulators
    for (int i = tid; i < 16 * 260; i += 1024) ((float*)ysf)[i] = 0.f;
    __syncthreads();

    // ---- phase 1: block-shared edge list, chunked across 16 waves ----
    {
        int s0 = start[m0];
        int e1 = (m0 + 16 < N_NODES) ? start[m0 + 16] : N_EDGES;
        int cntB = e1 - s0;
        int chunk = (cntB + 15) >> 4;
        int a = s0 + wid * chunk;
        int b = a + chunk; if (b > e1) b = e1;

        int slot = a;
        for (; slot + 3 < b; slot += 4) {
            uintx4 r0 = recs[2 * (size_t)(slot)];
            uintx4 r1 = recs[2 * (size_t)(slot + 1)];
            uintx4 r2 = recs[2 * (size_t)(slot + 2)];
            uintx4 r3 = recs[2 * (size_t)(slot + 3)];
            float h0 = bf2f(hb[(size_t)r0.x * 64 + lane]);
            float h1 = bf2f(hb[(size_t)r1.x * 64 + lane]);
            float h2 = bf2f(hb[(size_t)r2.x * 64 + lane]);
            float h3 = bf2f(hb[(size_t)r3.x * 64 + lane]);
            {
                float* row = &ysf[r0.w & 15][0];
                atomicAdd(row + lane,       bflo(r0.y) * h0);
                atomicAdd(row + 64 + lane,  bfhi(r0.y) * h0);
                atomicAdd(row + 128 + lane, bflo(r0.z) * h0);
                atomicAdd(row + 192 + lane, bfhi(r0.z) * h0);
            }
            {
                float* row = &ysf[r1.w & 15][0];
                atomicAdd(row + lane,       bflo(r1.y) * h1);
                atomicAdd(row + 64 + lane,  bfhi(r1.y) * h1);
                atomicAdd(row + 128 + lane, bflo(r1.z) * h1);
                atomicAdd(row + 192 + lane, bfhi(r1.z) * h1);
            }
            {
                float* row = &ysf[r2.w & 15][0];
                atomicAdd(row + lane,       bflo(r2.y) * h2);
                atomicAdd(row + 64 + lane,  bfhi(r2.y) * h2);
                atomicAdd(row + 128 + lane, bflo(r2.z) * h2);
                atomicAdd(row + 192 + lane, bfhi(r2.z) * h2);
            }
            {
                float* row = &ysf[r3.w & 15][0];
                atomicAdd(row + lane,       bflo(r3.y) * h3);
                atomicAdd(row + 64 + lane,  bfhi(r3.y) * h3);
                atomicAdd(row + 128 + lane, bflo(r3.z) * h3);
                atomicAdd(row + 192 + lane, bfhi(r3.z) * h3);
            }
        }
        for (; slot < b; ++slot) {
            uintx4 r = recs[2 * (size_t)slot];
            float hv = bf2f(hb[(size_t)r.x * 64 + lane]);
            float* row = &ysf[r.w & 15][0];
            atomicAdd(row + lane,       bflo(r.y) * hv);
            atomicAdd(row + 64 + lane,  bfhi(r.y) * hv);
            atomicAdd(row + 128 + lane, bflo(r.z) * hv);
            atomicAdd(row + 192 + lane, bfhi(r.z) * hv);
        }
    }
    __syncthreads();

    // ---- phase 2: waves 0..3, wave wid = col-tile wid ----
    if (wid < 4) {
        const int nlo = lane & 15;
        const int quad = lane >> 4;

        floatx4 acc = (floatx4){0.f, 0.f, 0.f, 0.f};
        const ushort* hrow = hb + (size_t)(m0 + nlo) * 64 + quad * 8;
        const uintx4* bptr = (const uintx4*)Bsw;

        #pragma unroll
        for (int kb = 0; kb < 10; ++kb) {
            short8 a;
            if (kb < 8) {
                const float* yr = &ysf[nlo][kb * 32 + quad * 8];
                #pragma unroll
                for (int j = 0; j < 8; ++j) a[j] = (short)f2bf(yr[j]);
            } else {
                a = __builtin_bit_cast(short8, *(const uintx4*)(hrow + (kb - 8) * 32));
            }
            short8 b = __builtin_bit_cast(short8, bptr[(kb * 4 + wid) * 64 + lane]);
            acc = __builtin_amdgcn_mfma_f32_16x16x32_bf16(a, b, acc, 0, 0, 0);
        }

        // C/D layout: col = wid*16 + (lane&15), row = quad*4 + reg
        int col = wid * 16 + nlo;
        float bv = bias[col];
        #pragma unroll
        for (int r = 0; r < 4; ++r) {
            int row = m0 + quad * 4 + r;
            float v = acc[r] + bv;
            if (relu) v = fmaxf(v, 0.f);
            if (outf) outf[(size_t)row * 64 + col] = v;
            if (outh) outh[(size_t)row * 64 + col] = f2bf(v);
        }
    }
}

// ---------------- launch ----------------

extern "C" void kernel_launch(void* const* d_in, const int* in_sizes, int n_in,
                              void* d_out, int out_size, void* d_ws, size_t ws_size,
                              hipStream_t stream) {
    const float* x     = (const float*)d_in[0];
    const int*   ei    = (const int*)d_in[1];
    const float* ea    = (const float*)d_in[2];
    const float* basis = (const float*)d_in[3];  // [2,4,64,64]
    const float* att   = (const float*)d_in[4];  // [2,8,4]
    const float* root  = (const float*)d_in[5];  // [2,64,64]
    const float* bias  = (const float*)d_in[6];  // [2,64]
    float* out = (float*)d_out;

    char* p = (char*)d_ws;
    uintx4* rec    = (uintx4*)p;  p += (size_t)N_EDGES * 32;        // 25.6 MB
    ushort* hb0    = (ushort*)p;  p += (size_t)N_NODES * 64 * 2;    //  6.4 MB (x bf16)
    ushort* hb1    = (ushort*)p;  p += (size_t)N_NODES * 64 * 2;    //  6.4 MB (h1 bf16)
    ushort* Bsw    = (ushort*)p;  p += (size_t)2 * 20480 * 2;       //  80 KB
    int*    counts = (int*)p;     p += (size_t)N_NODES * 4;
    int*    start  = (int*)p;     p += (size_t)N_NODES * 4;
    int*    cursor = (int*)p;     p += (size_t)N_NODES * 4;
    int*    bsums  = (int*)p;     p += 64 * 4;

    const int scan_blocks = (N_NODES + 1023) / 1024;  // 49

    (void)hipMemsetAsync(counts, 0, (size_t)N_NODES * 4, stream);
    setup_k<<<HIST_BLOCKS + CONV_BLOCKS + PREP_BLOCKS, 256, 0, stream>>>(
        ei, counts, x, hb0, basis, root, Bsw);
    scan1_k<<<scan_blocks, 1024, 0, stream>>>(counts, start, bsums);
    scan2_k<<<1, 64, 0, stream>>>(bsums, scan_blocks);
    scan3_k<<<(N_NODES + 255) / 256, 256, 0, stream>>>(start, cursor, bsums);
    scatter_k<<<HIST_BLOCKS, 256, 0, stream>>>(ei, ea, att, cursor, rec);

    dim3 fuse_grid(N_NODES / 16);   // 3125, 1024 threads each

    // ---- layer 0: h = x (hb0) -> h1 bf16 (hb1) ----
    aggmm_k<<<fuse_grid, 1024, 0, stream>>>(start, rec, hb0, Bsw, bias,
                                            (float*)0, hb1, 1);
    // ---- layer 1: h = h1 (hb1) -> out fp32 ----
    aggmm_k<<<fuse_grid, 1024, 0, stream>>>(start, rec + 1, hb1, Bsw + 20480, bias + 64,
                                            out, (ushort*)0, 0);
}